// Round 2
// baseline (385.971 us; speedup 1.0000x reference)
//
#include <hip/hip_runtime.h>
#include <math.h>

#define M_DIM 1024
#define K_DIM 32
#define N_DIM 2048
#define PGD_ITERS 1500
#define POW_ITERS 12

// ws layout (float offsets)
#define G_OFF   0        // 32*32 = 1024 floats
#define T_OFF   2048     // 32*2048 = 65536 floats

// Broadcast lane `lane`'s value of x to all 64 lanes via v_readlane (VALU,
// lands in an SGPR -> legal single-SGPR operand of the consuming FMA).
__device__ __forceinline__ float bcast_lane(float x, int lane) {
    return __int_as_float(__builtin_amdgcn_readlane(__float_as_int(x), lane));
}

// ---------------------------------------------------------------------------
// G = theta_c^T theta_c, theta_c = max(theta, 0).  One block per entry (i,j).
__global__ void kGram(const float* __restrict__ theta, float* __restrict__ G) {
    int e = blockIdx.x;           // 0..1023
    int i = e >> 5, j = e & 31;
    int tid = threadIdx.x;        // 256 threads
    float p = 0.f;
    for (int m = tid; m < M_DIM; m += 256) {
        float a = fmaxf(theta[m * K_DIM + i], 0.f);
        float b = fmaxf(theta[m * K_DIM + j], 0.f);
        p = fmaf(a, b, p);
    }
    __shared__ float red[256];
    red[tid] = p;
    __syncthreads();
    for (int s = 128; s > 0; s >>= 1) {
        if (tid < s) red[tid] += red[tid + s];
        __syncthreads();
    }
    if (tid == 0) G[e] = red[0];
}

// ---------------------------------------------------------------------------
// T = theta_c^T X  (32 x 2048).  grid = (8 col-blocks, 8 m-splits), block 256.
__global__ void kTmat(const float* __restrict__ X, const float* __restrict__ theta,
                      float* __restrict__ T) {
    __shared__ float th[128][32];
    int tid = threadIdx.x;
    int m0 = blockIdx.y * 128;
#pragma unroll
    for (int q = 0; q < 16; ++q) {
        int e = q * 256 + tid;            // 0..4095, coalesced
        th[e >> 5][e & 31] = fmaxf(theta[(m0 + (e >> 5)) * K_DIM + (e & 31)], 0.f);
    }
    __syncthreads();
    int col = blockIdx.x * 256 + tid;
    float acc[32];
#pragma unroll
    for (int i = 0; i < 32; ++i) acc[i] = 0.f;
    for (int mm = 0; mm < 128; ++mm) {
        float x = X[(m0 + mm) * N_DIM + col];
#pragma unroll
        for (int i = 0; i < 32; ++i) acc[i] = fmaf(th[mm][i], x, acc[i]);
    }
#pragma unroll
    for (int i = 0; i < 32; ++i) atomicAdd(&T[i * N_DIM + col], acc[i]);
}

// ---------------------------------------------------------------------------
// PGD with register-resident b and readlane broadcast.  One column per wave
// (lane i in 0..31 owns b_i; upper half duplicates).  Zero LDS/DS ops in the
// 1500-iteration loop.  Wave 0 of each block first runs 12 power iterations
// (register G row + readlane) to get L = lambda_max + 1e-6.
__global__ void __launch_bounds__(256) kPGD(const float* __restrict__ G,
                                            const float* __restrict__ T,
                                            float* __restrict__ out) {
    __shared__ float Gsh[32][33];
    __shared__ float lamsh;
    int tid = threadIdx.x;
#pragma unroll
    for (int q = 0; q < 4; ++q) {
        int e = q * 256 + tid;
        Gsh[e >> 5][e & 31] = G[e];
    }
    __syncthreads();

    int i = tid & 31;
    int wv = tid >> 6;                    // wave in block: 0..3
    int col = blockIdx.x * 4 + wv;

    float g[32];
#pragma unroll
    for (int j = 0; j < 32; ++j) g[j] = Gsh[i][j];

    // --- power iteration (wave 0 only, fully in registers) ---
    if (tid < 64) {
        float v = 1.f, lam = 1.f;
        for (int p = 0; p < POW_ITERS; ++p) {
            float w = 0.f;
#pragma unroll
            for (int j = 0; j < 32; ++j) w = fmaf(g[j], bcast_lane(v, j), w);
            float n2 = w * w;
#pragma unroll
            for (int m = 1; m < 32; m <<= 1) n2 += __shfl_xor(n2, m, 32);
            lam = sqrtf(n2);
            v = w / lam;
        }
        if (tid == 0) lamsh = lam + 1e-6f;
    }
    __syncthreads();

    float invL = 1.0f / lamsh;
    float ar[32];
#pragma unroll
    for (int j = 0; j < 32; ++j)
        ar[j] = ((j == i) ? 1.0f : 0.0f) - g[j] * invL;
    float t = T[i * N_DIM + col] * invL;

    // --- main loop: b <- max(A b + t, 0), exchange via readlane only ---
    float bn = 0.f;
    for (int it = 0; it < PGD_ITERS; ++it) {
        float acc[4];
        acc[0] = t; acc[1] = 0.f; acc[2] = 0.f; acc[3] = 0.f;
#pragma unroll
        for (int j = 0; j < 32; ++j) {
            float bj = bcast_lane(bn, j);
            acc[j & 3] = fmaf(ar[j], bj, acc[j & 3]);
        }
        bn = fmaxf((acc[0] + acc[1]) + (acc[2] + acc[3]), 0.f);
    }
    if ((tid & 32) == 0) out[i * N_DIM + col] = bn;
}

// ---------------------------------------------------------------------------
extern "C" void kernel_launch(void* const* d_in, const int* in_sizes, int n_in,
                              void* d_out, int out_size, void* d_ws, size_t ws_size,
                              hipStream_t stream) {
    const float* X     = (const float*)d_in[0];   // (1024, 2048) f32
    const float* theta = (const float*)d_in[1];   // (1024, 32) f32
    float* ws = (float*)d_ws;
    float* G  = ws + G_OFF;
    float* T  = ws + T_OFF;

    hipMemsetAsync(T, 0, (size_t)K_DIM * N_DIM * sizeof(float), stream);
    kGram<<<1024, 256, 0, stream>>>(theta, G);
    kTmat<<<dim3(8, 8), 256, 0, stream>>>(X, theta, T);
    kPGD<<<512, 256, 0, stream>>>(G, T, (float*)d_out);
}

// Round 8
// 217.014 us; speedup vs baseline: 1.7786x; 1.7786x over previous
//
#include <hip/hip_runtime.h>
#include <math.h>

#define M_DIM 1024
#define K_DIM 32
#define N_DIM 2048
#define ACC_ITERS 550      // Nesterov (strongly-convex momentum) iterations
#define POLISH_ITERS 50    // trailing plain-PGD polish
#define POW_ITERS 12       // power iterations for lambda_max (gap ratio ~0.014)

// ws layout (float offsets)
#define G_OFF   0          // 32*32 floats
#define T_OFF   2048       // 32*2048 floats

// v_readlane_b32: VALU, result in SGPR -> legal single-SGPR FMA operand.
__device__ __forceinline__ float bcast_lane(float x, int lane) {
    return __int_as_float(__builtin_amdgcn_readlane(__float_as_int(x), lane));
}

// ---------------------------------------------------------------------------
// One prep kernel, write-once (no atomics, no memset).
// Blocks 0..31:   G row i  (G = theta_c^T theta_c, theta_c = max(theta,0))
// Blocks 32..95:  T tile of 32 columns (T = theta_c^T X), theta staged in LDS
//                 in two 512-row phases (64 KB).
__global__ void __launch_bounds__(256) kPrep(const float* __restrict__ X,
                                             const float* __restrict__ theta,
                                             float* __restrict__ G,
                                             float* __restrict__ T) {
    __shared__ float th[512][32];              // 64 KB, reused as reduce buffer
    int tid = threadIdx.x;
    int bid = blockIdx.x;

    if (bid < 32) {
        // ---- G row i ----
        int i = bid;
        int j  = tid & 31;
        int ms = tid >> 5;                     // 8 m-slices x 128
        float p = 0.f;
        for (int mq = 0; mq < 128; ++mq) {
            int m = ms * 128 + mq;
            float a = fmaxf(theta[m * K_DIM + i], 0.f);
            float b = fmaxf(theta[m * K_DIM + j], 0.f);
            p = fmaf(a, b, p);
        }
        float (*red)[32] = (float (*)[32])th;
        red[ms][j] = p;
        __syncthreads();
        if (ms == 0) {
            float s = p;
            for (int q = 1; q < 8; ++q) s += red[q][j];
            G[i * 32 + j] = s;
        }
        return;
    }

    // ---- T tile ----
    int tb = bid - 32;                         // 0..63
    int lc = tid & 31;
    int c  = tb * 32 + lc;
    int ms = tid >> 5;                         // 8 m-slices
    float acc[32];
#pragma unroll
    for (int i = 0; i < 32; ++i) acc[i] = 0.f;

    for (int ph = 0; ph < 2; ++ph) {
        // stage clamped theta rows [ph*512, ph*512+512) into LDS, coalesced
        for (int q = 0; q < 64; ++q) {
            int e = q * 256 + tid;             // 0..16383
            th[e >> 5][e & 31] =
                fmaxf(theta[(ph * 512 + (e >> 5)) * K_DIM + (e & 31)], 0.f);
        }
        __syncthreads();
        for (int mq = 0; mq < 64; ++mq) {
            int m = ms * 64 + mq;              // local row in [0,512)
            float x = X[(ph * 512 + m) * N_DIM + c];
#pragma unroll
            for (int i = 0; i < 32; ++i) acc[i] = fmaf(th[m][i], x, acc[i]);
        }
        __syncthreads();
    }

    // reduce the 8 m-slices via LDS (reuse th)
    float* rbuf = &th[0][0];                   // [ms][i][c] = ms*1024 + i*32 + c
#pragma unroll
    for (int i = 0; i < 32; ++i) rbuf[ms * 1024 + i * 32 + lc] = acc[i];
    __syncthreads();
    for (int q = 0; q < 4; ++q) {
        int e = q * 256 + tid;                 // i = e>>5, cc = e&31
        float s = 0.f;
        for (int s8 = 0; s8 < 8; ++s8) s += rbuf[s8 * 1024 + e];
        T[(e >> 5) * N_DIM + tb * 32 + (e & 31)] = s;
    }
}

// ---------------------------------------------------------------------------
// Accelerated projected gradient, register-resident, readlane broadcast.
// One column per wave (upper 32 lanes duplicate).  Wave 0 computes
// L = lambda_max(G)+1e-6 (power iter) and mu' = 0.25*(tr(G)-lambda)/31
// (deliberate under-estimate -> momentum remains convergent), then
// beta = (sqrt(L)-sqrt(mu'))/(sqrt(L)+sqrt(mu')).
__global__ void __launch_bounds__(256, 2) kPGD(const float* __restrict__ G,
                                               const float* __restrict__ T,
                                               float* __restrict__ out) {
    __shared__ float Gsh[32][33];
    __shared__ float lamsh, betash;
    int tid = threadIdx.x;
#pragma unroll
    for (int q = 0; q < 4; ++q) {
        int e = q * 256 + tid;
        Gsh[e >> 5][e & 31] = G[e];
    }
    __syncthreads();

    int i  = tid & 31;
    int wv = tid >> 6;
    int col = blockIdx.x * 4 + wv;

    float g[32];
#pragma unroll
    for (int j = 0; j < 32; ++j) g[j] = Gsh[i][j];

    // --- wave 0: lambda_max + mu estimate ---
    if (tid < 64) {
        float v = 1.f, lam = 1.f;
        for (int p = 0; p < POW_ITERS; ++p) {
            float w = 0.f;
#pragma unroll
            for (int j = 0; j < 32; ++j) w = fmaf(g[j], bcast_lane(v, j), w);
            float n2 = w * w;
#pragma unroll
            for (int m = 1; m < 32; m <<= 1) n2 += __shfl_xor(n2, m, 32);
            lam = sqrtf(n2);
            v = w / lam;
        }
        float d = Gsh[i][i];                    // trace
#pragma unroll
        for (int m = 1; m < 32; m <<= 1) d += __shfl_xor(d, m, 32);
        if (tid == 0) {
            float L  = lam + 1e-6f;
            float mu = 0.25f * (d - lam) * (1.0f / 31.0f);
            mu = fmaxf(mu, 1e-3f * L);
            float sL = sqrtf(L), sm = sqrtf(mu);
            lamsh  = L;
            betash = (sL - sm) / (sL + sm);
        }
    }
    __syncthreads();

    float invL = 1.0f / lamsh;
    float beta = betash;
    float ar[32];
#pragma unroll
    for (int j = 0; j < 32; ++j)
        ar[j] = ((j == i) ? 1.0f : 0.0f) - g[j] * invL;
    float t = T[i * N_DIM + col] * invL;

    // Clobber Gsh so the compiler cannot rematerialize ar[] from LDS
    // (round-2 VGPR_Count=24 showed it re-read LDS every iteration).
    __syncthreads();
    if (tid == 0) Gsh[0][0] = 0.f;
    __syncthreads();

    // --- accelerated loop: w = max(A y + t, 0); y = w + beta (w - w_prev) ---
    float y = 0.f, bprev = 0.f;
    for (int it = 0; it < ACC_ITERS; ++it) {
        float a0 = t, a1 = 0.f, a2 = 0.f, a3 = 0.f;
#pragma unroll
        for (int j = 0; j < 32; ++j) {
            float bj = bcast_lane(y, j);
            if ((j & 3) == 0)      a0 = fmaf(ar[j], bj, a0);
            else if ((j & 3) == 1) a1 = fmaf(ar[j], bj, a1);
            else if ((j & 3) == 2) a2 = fmaf(ar[j], bj, a2);
            else                   a3 = fmaf(ar[j], bj, a3);
        }
        float w = fmaxf((a0 + a1) + (a2 + a3), 0.f);
        y = fmaf(beta, w - bprev, w);
        bprev = w;
    }
    // --- plain-PGD polish (damps momentum wobble, monotone contraction) ---
    for (int it = 0; it < POLISH_ITERS; ++it) {
        float a0 = t, a1 = 0.f, a2 = 0.f, a3 = 0.f;
#pragma unroll
        for (int j = 0; j < 32; ++j) {
            float bj = bcast_lane(y, j);
            if ((j & 3) == 0)      a0 = fmaf(ar[j], bj, a0);
            else if ((j & 3) == 1) a1 = fmaf(ar[j], bj, a1);
            else if ((j & 3) == 2) a2 = fmaf(ar[j], bj, a2);
            else                   a3 = fmaf(ar[j], bj, a3);
        }
        y = fmaxf((a0 + a1) + (a2 + a3), 0.f);
    }

    if ((tid & 32) == 0) out[i * N_DIM + col] = y;
}

// ---------------------------------------------------------------------------
extern "C" void kernel_launch(void* const* d_in, const int* in_sizes, int n_in,
                              void* d_out, int out_size, void* d_ws, size_t ws_size,
                              hipStream_t stream) {
    const float* X     = (const float*)d_in[0];   // (1024, 2048) f32
    const float* theta = (const float*)d_in[1];   // (1024, 32) f32
    float* ws = (float*)d_ws;
    float* G  = ws + G_OFF;
    float* T  = ws + T_OFF;

    kPrep<<<96, 256, 0, stream>>>(X, theta, G, T);
    kPGD<<<512, 256, 0, stream>>>(G, T, (float*)d_out);
}

// Round 9
// 215.364 us; speedup vs baseline: 1.7922x; 1.0077x over previous
//
#include <hip/hip_runtime.h>
#include <math.h>

#define M_DIM 1024
#define K_DIM 32
#define N_DIM 2048
#define ACC_ITERS 550      // Nesterov (strongly-convex momentum) iterations
#define POLISH_ITERS 50    // trailing plain-PGD polish
#define POW_ITERS 12       // power iterations for lambda_max (gap ratio ~0.014)

// ws layout (float offsets)
#define G_OFF    0         // 32*32 floats
#define THC_OFF  2048      // 1024*32 clamped theta
#define T_OFF    36864     // 32*2048 floats

// v_readlane_b32: VALU, result in SGPR -> legal single-SGPR FMA operand.
__device__ __forceinline__ float bcast_lane(float x, int lane) {
    return __int_as_float(__builtin_amdgcn_readlane(__float_as_int(x), lane));
}

// ---------------------------------------------------------------------------
// kA: blocks 0..31 compute G row i (G = theta_c^T theta_c);
//     blocks 32..159 clamp theta -> thc (32768 elems, 256/block).
__global__ void __launch_bounds__(256) kA(const float* __restrict__ theta,
                                          float* __restrict__ G,
                                          float* __restrict__ thc) {
    int tid = threadIdx.x;
    int bid = blockIdx.x;

    if (bid >= 32) {
        int e = (bid - 32) * 256 + tid;       // 0..32767, coalesced
        thc[e] = fmaxf(theta[e], 0.f);
        return;
    }

    // ---- G row i ----
    __shared__ float red[8][32];
    int i  = bid;
    int j  = tid & 31;
    int ms = tid >> 5;                        // 8 m-slices x 128
    float p = 0.f;
    for (int mq = 0; mq < 128; ++mq) {
        int m = ms * 128 + mq;
        float a = fmaxf(theta[m * K_DIM + i], 0.f);
        float b = fmaxf(theta[m * K_DIM + j], 0.f);
        p = fmaf(a, b, p);
    }
    red[ms][j] = p;
    __syncthreads();
    if (ms == 0) {
        float s = p;
        for (int q = 1; q < 8; ++q) s += red[q][j];
        G[i * 32 + j] = s;
    }
}

// ---------------------------------------------------------------------------
// kT: T = thc^T X.  grid (8 col-blocks, 8 m-slices), 256 threads; thread owns
// one column c.  thc rows are lane-invariant -> float4 loads broadcast from
// L1 (no LDS re-read storm).  atomicAdd combines the 8 m-slices.
__global__ void __launch_bounds__(256) kT(const float* __restrict__ X,
                                          const float* __restrict__ thc,
                                          float* __restrict__ T) {
    int tid = threadIdx.x;
    int c   = blockIdx.x * 256 + tid;
    int m0  = blockIdx.y * 128;

    float acc[32];
#pragma unroll
    for (int i = 0; i < 32; ++i) acc[i] = 0.f;

    for (int m = 0; m < 128; ++m) {
        int row = m0 + m;
        float x = X[row * N_DIM + c];
        const float4* t4 = reinterpret_cast<const float4*>(thc + row * K_DIM);
#pragma unroll
        for (int q = 0; q < 8; ++q) {
            float4 v = t4[q];
            acc[4 * q + 0] = fmaf(v.x, x, acc[4 * q + 0]);
            acc[4 * q + 1] = fmaf(v.y, x, acc[4 * q + 1]);
            acc[4 * q + 2] = fmaf(v.z, x, acc[4 * q + 2]);
            acc[4 * q + 3] = fmaf(v.w, x, acc[4 * q + 3]);
        }
    }
#pragma unroll
    for (int i = 0; i < 32; ++i) atomicAdd(&T[i * N_DIM + c], acc[i]);
}

// ---------------------------------------------------------------------------
// Accelerated projected gradient, register-resident, readlane broadcast.
// One column per wave (upper 32 lanes duplicate).  Wave 0 computes
// L = lambda_max(G)+1e-6 (power iter) and mu' = 0.25*(tr(G)-lambda)/31,
// then beta = (sqrt(L)-sqrt(mu'))/(sqrt(L)+sqrt(mu')).
__global__ void __launch_bounds__(256, 2) kPGD(const float* __restrict__ G,
                                               const float* __restrict__ T,
                                               float* __restrict__ out) {
    __shared__ float Gsh[32][33];
    __shared__ float lamsh, betash;
    int tid = threadIdx.x;
#pragma unroll
    for (int q = 0; q < 4; ++q) {
        int e = q * 256 + tid;
        Gsh[e >> 5][e & 31] = G[e];
    }
    __syncthreads();

    int i  = tid & 31;
    int wv = tid >> 6;
    int col = blockIdx.x * 4 + wv;

    float g[32];
#pragma unroll
    for (int j = 0; j < 32; ++j) g[j] = Gsh[i][j];

    // --- wave 0: lambda_max + mu estimate ---
    if (tid < 64) {
        float v = 1.f, lam = 1.f;
        for (int p = 0; p < POW_ITERS; ++p) {
            float w = 0.f;
#pragma unroll
            for (int j = 0; j < 32; ++j) w = fmaf(g[j], bcast_lane(v, j), w);
            float n2 = w * w;
#pragma unroll
            for (int m = 1; m < 32; m <<= 1) n2 += __shfl_xor(n2, m, 32);
            lam = sqrtf(n2);
            v = w / lam;
        }
        float d = Gsh[i][i];                    // trace
#pragma unroll
        for (int m = 1; m < 32; m <<= 1) d += __shfl_xor(d, m, 32);
        if (tid == 0) {
            float L  = lam + 1e-6f;
            float mu = 0.25f * (d - lam) * (1.0f / 31.0f);
            mu = fmaxf(mu, 1e-3f * L);
            float sL = sqrtf(L), sm = sqrtf(mu);
            lamsh  = L;
            betash = (sL - sm) / (sL + sm);
        }
    }
    __syncthreads();

    float invL = 1.0f / lamsh;
    float beta = betash;

    // ar[] pinned opaque in VGPRs: round-2/8 showed VGPR_Count=24 -> the
    // compiler rematerialized ar[j] from LDS every iteration.  The empty asm
    // makes each value's provenance opaque, forcing register residency.
    float ar[32];
#pragma unroll
    for (int j = 0; j < 32; ++j) {
        ar[j] = ((j == i) ? 1.0f : 0.0f) - g[j] * invL;
        asm volatile("" : "+v"(ar[j]));
    }
    float t = T[i * N_DIM + col] * invL;

    // --- accelerated loop: w = max(A y + t, 0); y = w + beta (w - w_prev) ---
    float y = 0.f, bprev = 0.f;
    for (int it = 0; it < ACC_ITERS; ++it) {
        float a0 = t, a1 = 0.f, a2 = 0.f, a3 = 0.f;
#pragma unroll
        for (int j = 0; j < 32; ++j) {
            float bj = bcast_lane(y, j);
            if ((j & 3) == 0)      a0 = fmaf(ar[j], bj, a0);
            else if ((j & 3) == 1) a1 = fmaf(ar[j], bj, a1);
            else if ((j & 3) == 2) a2 = fmaf(ar[j], bj, a2);
            else                   a3 = fmaf(ar[j], bj, a3);
        }
        float w = fmaxf((a0 + a1) + (a2 + a3), 0.f);
        y = fmaf(beta, w - bprev, w);
        bprev = w;
    }
    // --- plain-PGD polish (damps momentum wobble, monotone contraction) ---
    for (int it = 0; it < POLISH_ITERS; ++it) {
        float a0 = t, a1 = 0.f, a2 = 0.f, a3 = 0.f;
#pragma unroll
        for (int j = 0; j < 32; ++j) {
            float bj = bcast_lane(y, j);
            if ((j & 3) == 0)      a0 = fmaf(ar[j], bj, a0);
            else if ((j & 3) == 1) a1 = fmaf(ar[j], bj, a1);
            else if ((j & 3) == 2) a2 = fmaf(ar[j], bj, a2);
            else                   a3 = fmaf(ar[j], bj, a3);
        }
        y = fmaxf((a0 + a1) + (a2 + a3), 0.f);
    }

    if ((tid & 32) == 0) out[i * N_DIM + col] = y;
}

// ---------------------------------------------------------------------------
extern "C" void kernel_launch(void* const* d_in, const int* in_sizes, int n_in,
                              void* d_out, int out_size, void* d_ws, size_t ws_size,
                              hipStream_t stream) {
    const float* X     = (const float*)d_in[0];   // (1024, 2048) f32
    const float* theta = (const float*)d_in[1];   // (1024, 32) f32
    float* ws  = (float*)d_ws;
    float* G   = ws + G_OFF;
    float* thc = ws + THC_OFF;
    float* T   = ws + T_OFF;

    hipMemsetAsync(T, 0, (size_t)K_DIM * N_DIM * sizeof(float), stream);
    kA<<<160, 256, 0, stream>>>(theta, G, thc);
    kT<<<dim3(8, 8), 256, 0, stream>>>(X, thc, T);
    kPGD<<<512, 256, 0, stream>>>(G, T, (float*)d_out);
}

// Round 10
// 181.941 us; speedup vs baseline: 2.1214x; 1.1837x over previous
//
#include <hip/hip_runtime.h>
#include <math.h>

#define M_DIM 1024
#define K_DIM 32
#define N_DIM 2048
#define ACC_ITERS 350      // Nesterov (strongly-convex momentum) iterations
#define POLISH_ITERS 50    // trailing plain-PGD polish
#define POW_ITERS 12       // power iterations for lambda_max (gap ratio ~0.014)

// ws layout (float offsets)
#define G_OFF    0         // 32*32 floats
#define THC_OFF  2048      // 1024*32 clamped theta
#define T_OFF    36864     // 32*2048 floats

// v_readlane_b32: VALU, result in SGPR -> legal single-SGPR FMA operand.
__device__ __forceinline__ float bcast_lane(float x, int lane) {
    return __int_as_float(__builtin_amdgcn_readlane(__float_as_int(x), lane));
}

// ---------------------------------------------------------------------------
// kA: blocks 0..31 compute G row i (G = theta_c^T theta_c);
//     blocks 32..159 clamp theta -> thc (32768 elems, 256/block).
__global__ void __launch_bounds__(256) kA(const float* __restrict__ theta,
                                          float* __restrict__ G,
                                          float* __restrict__ thc) {
    int tid = threadIdx.x;
    int bid = blockIdx.x;

    if (bid >= 32) {
        int e = (bid - 32) * 256 + tid;       // 0..32767, coalesced
        thc[e] = fmaxf(theta[e], 0.f);
        return;
    }

    // ---- G row i ----
    __shared__ float red[8][32];
    int i  = bid;
    int j  = tid & 31;
    int ms = tid >> 5;                        // 8 m-slices x 128
    float p = 0.f;
    for (int mq = 0; mq < 128; ++mq) {
        int m = ms * 128 + mq;
        float a = fmaxf(theta[m * K_DIM + i], 0.f);
        float b = fmaxf(theta[m * K_DIM + j], 0.f);
        p = fmaf(a, b, p);
    }
    red[ms][j] = p;
    __syncthreads();
    if (ms == 0) {
        float s = p;
        for (int q = 1; q < 8; ++q) s += red[q][j];
        G[i * 32 + j] = s;
    }
}

// ---------------------------------------------------------------------------
// kT: T = thc^T X.  grid (8 col-blocks, 8 m-slices), 256 threads; thread owns
// one column c.  thc rows are lane-invariant -> float4 loads broadcast from
// L1.  atomicAdd combines the 8 m-slices.
__global__ void __launch_bounds__(256) kT(const float* __restrict__ X,
                                          const float* __restrict__ thc,
                                          float* __restrict__ T) {
    int tid = threadIdx.x;
    int c   = blockIdx.x * 256 + tid;
    int m0  = blockIdx.y * 128;

    float acc[32];
#pragma unroll
    for (int i = 0; i < 32; ++i) acc[i] = 0.f;

    for (int m = 0; m < 128; ++m) {
        int row = m0 + m;
        float x = X[row * N_DIM + c];
        const float4* t4 = reinterpret_cast<const float4*>(thc + row * K_DIM);
#pragma unroll
        for (int q = 0; q < 8; ++q) {
            float4 v = t4[q];
            acc[4 * q + 0] = fmaf(v.x, x, acc[4 * q + 0]);
            acc[4 * q + 1] = fmaf(v.y, x, acc[4 * q + 1]);
            acc[4 * q + 2] = fmaf(v.z, x, acc[4 * q + 2]);
            acc[4 * q + 3] = fmaf(v.w, x, acc[4 * q + 3]);
        }
    }
#pragma unroll
    for (int i = 0; i < 32; ++i) atomicAdd(&T[i * N_DIM + c], acc[i]);
}

// ---------------------------------------------------------------------------
// Accelerated projected gradient, register-resident, readlane broadcast.
// One column per wave (upper 32 lanes duplicate).  Wave 0 computes
// L = lambda_max(G)+1e-6 (power iter) and mu' = 0.25*(tr(G)-lambda)/31,
// then beta = (sqrt(L)-sqrt(mu'))/(sqrt(L)+sqrt(mu')).
__global__ void __launch_bounds__(256, 2) kPGD(const float* __restrict__ G,
                                               const float* __restrict__ T,
                                               float* __restrict__ out) {
    __shared__ float Gsh[32][33];
    __shared__ float lamsh, betash;
    int tid = threadIdx.x;
#pragma unroll
    for (int q = 0; q < 4; ++q) {
        int e = q * 256 + tid;
        Gsh[e >> 5][e & 31] = G[e];
    }
    __syncthreads();

    int i  = tid & 31;
    int wv = tid >> 6;
    int col = blockIdx.x * 4 + wv;

    float g[32];
#pragma unroll
    for (int j = 0; j < 32; ++j) g[j] = Gsh[i][j];

    // --- wave 0: lambda_max + mu estimate ---
    if (tid < 64) {
        float v = 1.f, lam = 1.f;
        for (int p = 0; p < POW_ITERS; ++p) {
            float w = 0.f;
#pragma unroll
            for (int j = 0; j < 32; ++j) w = fmaf(g[j], bcast_lane(v, j), w);
            float n2 = w * w;
#pragma unroll
            for (int m = 1; m < 32; m <<= 1) n2 += __shfl_xor(n2, m, 32);
            lam = sqrtf(n2);
            v = w / lam;
        }
        float d = Gsh[i][i];                    // trace
#pragma unroll
        for (int m = 1; m < 32; m <<= 1) d += __shfl_xor(d, m, 32);
        if (tid == 0) {
            float L  = lam + 1e-6f;
            float mu = 0.25f * (d - lam) * (1.0f / 31.0f);
            mu = fmaxf(mu, 1e-3f * L);
            float sL = sqrtf(L), sm = sqrtf(mu);
            lamsh  = L;
            betash = (sL - sm) / (sL + sm);
        }
    }
    __syncthreads();

    float invL = 1.0f / lamsh;
    float beta = betash;

    float ar[32];
#pragma unroll
    for (int j = 0; j < 32; ++j) {
        ar[j] = ((j == i) ? 1.0f : 0.0f) - g[j] * invL;
        asm volatile("" : "+v"(ar[j]));
    }
    float t = T[i * N_DIM + col] * invL;

    // FULL clobber of Gsh: rounds 8/9 only overwrote [0][0], so the compiler
    // legally rematerialized ar[j] from Gsh[i][j] (j!=0) every iteration
    // (~34 extra inst/iter).  Zeroing ALL entries destroys the remat source.
    __syncthreads();
#pragma unroll
    for (int q = 0; q < 4; ++q) {
        int e = q * 256 + tid;
        Gsh[e >> 5][e & 31] = 0.f;
    }
    __syncthreads();
    // Non-foldable read (no fast-math: x*0+t != t in general) keeps the
    // zero-stores alive and is an exact no-op here (Gsh==0).
    t = fmaf(Gsh[i][(tid * 7) & 31], 0.0f, t);

    // --- accelerated loop: w = max(A y + t, 0); y = w + beta (w - w_prev) ---
    // Readlanes hoisted into a batch: all 32 depend only on y, so they can
    // issue back-to-back; the FMA chain then consumes SGPRs without
    // per-pair VALU->SGPR->VALU hazard stalls.
    float y = 0.f, bprev = 0.f;
    for (int it = 0; it < ACC_ITERS; ++it) {
        float bj[32];
#pragma unroll
        for (int j = 0; j < 32; ++j) bj[j] = bcast_lane(y, j);
        float a0 = t, a1 = 0.f, a2 = 0.f, a3 = 0.f;
#pragma unroll
        for (int j = 0; j < 32; j += 4) {
            a0 = fmaf(ar[j + 0], bj[j + 0], a0);
            a1 = fmaf(ar[j + 1], bj[j + 1], a1);
            a2 = fmaf(ar[j + 2], bj[j + 2], a2);
            a3 = fmaf(ar[j + 3], bj[j + 3], a3);
        }
        float w = fmaxf((a0 + a1) + (a2 + a3), 0.f);
        y = fmaf(beta, w - bprev, w);
        bprev = w;
    }
    // --- plain-PGD polish (damps momentum wobble, monotone contraction) ---
    for (int it = 0; it < POLISH_ITERS; ++it) {
        float bj[32];
#pragma unroll
        for (int j = 0; j < 32; ++j) bj[j] = bcast_lane(y, j);
        float a0 = t, a1 = 0.f, a2 = 0.f, a3 = 0.f;
#pragma unroll
        for (int j = 0; j < 32; j += 4) {
            a0 = fmaf(ar[j + 0], bj[j + 0], a0);
            a1 = fmaf(ar[j + 1], bj[j + 1], a1);
            a2 = fmaf(ar[j + 2], bj[j + 2], a2);
            a3 = fmaf(ar[j + 3], bj[j + 3], a3);
        }
        y = fmaxf((a0 + a1) + (a2 + a3), 0.f);
    }

    if ((tid & 32) == 0) out[i * N_DIM + col] = y;
}

// ---------------------------------------------------------------------------
extern "C" void kernel_launch(void* const* d_in, const int* in_sizes, int n_in,
                              void* d_out, int out_size, void* d_ws, size_t ws_size,
                              hipStream_t stream) {
    const float* X     = (const float*)d_in[0];   // (1024, 2048) f32
    const float* theta = (const float*)d_in[1];   // (1024, 32) f32
    float* ws  = (float*)d_ws;
    float* G   = ws + G_OFF;
    float* thc = ws + THC_OFF;
    float* T   = ws + T_OFF;

    hipMemsetAsync(T, 0, (size_t)K_DIM * N_DIM * sizeof(float), stream);
    kA<<<160, 256, 0, stream>>>(theta, G, thc);
    kT<<<dim3(8, 8), 256, 0, stream>>>(X, thc, T);
    kPGD<<<512, 256, 0, stream>>>(G, T, (float*)d_out);
}